// Round 1
// baseline (407.284 us; speedup 1.0000x reference)
//
#include <hip/hip_runtime.h>

typedef float fx4 __attribute__((ext_vector_type(4)));
typedef short s16x8 __attribute__((ext_vector_type(8)));
typedef unsigned short ushort_t;

__device__ __forceinline__ short f2bf(float f) {
  union { float f; unsigned u; } v; v.f = f;
  unsigned r = v.u + 0x7FFFu + ((v.u >> 16) & 1u);   // RNE to bf16
  return (short)(r >> 16);
}

// ---------------------------------------------------------------------------
// Generic fp32 GEMM: C[M,N] = A[M,K] @ B[K,N] + bias (+res)(+relu)
// tile 128x64, 256 threads, 8x4 per-thread microtile.
// OUTMODE 0: fp32 C. OUTMODE 1: bf16, transposed (C[n][m]) for MFMA B operand.
// ---------------------------------------------------------------------------
template<int OUTMODE, bool RELU, bool RES>
__global__ __launch_bounds__(256) void gemm128(
    const float* __restrict__ A, const float* __restrict__ B,
    const float* __restrict__ bias, const float* __restrict__ res,
    void* __restrict__ Cv, int M, int N, int K) {
  __shared__ float As[16][136];   // As[k][m], stride 136 (16B aligned, banks spread)
  __shared__ float Bs[16][68];    // Bs[k][n]
  const int t = threadIdx.x;
  const int bm = blockIdx.y * 128, bn = blockIdx.x * 64;
  const int tmr = (t >> 4) * 8;
  const int tnc = (t & 15) * 4;
  const int am = t >> 1, ak = (t & 1) * 8;
  const int bk = t >> 4, bn2 = (t & 15) * 4;
  float acc[8][4] = {};
  for (int k0 = 0; k0 < K; k0 += 16) {
    fx4 av0 = *(const fx4*)(A + (size_t)(bm + am) * K + k0 + ak);
    fx4 av1 = *(const fx4*)(A + (size_t)(bm + am) * K + k0 + ak + 4);
    fx4 bv  = *(const fx4*)(B + (size_t)(k0 + bk) * N + bn + bn2);
    __syncthreads();
    #pragma unroll
    for (int i = 0; i < 4; ++i) As[ak + i][am] = av0[i];
    #pragma unroll
    for (int i = 0; i < 4; ++i) As[ak + 4 + i][am] = av1[i];
    *(fx4*)&Bs[bk][bn2] = bv;
    __syncthreads();
    #pragma unroll
    for (int kk = 0; kk < 16; ++kk) {
      fx4 a0 = *(const fx4*)&As[kk][tmr];
      fx4 a1 = *(const fx4*)&As[kk][tmr + 4];
      fx4 b  = *(const fx4*)&Bs[kk][tnc];
      #pragma unroll
      for (int j = 0; j < 4; ++j) {
        acc[0][j] += a0[0] * b[j];  acc[1][j] += a0[1] * b[j];
        acc[2][j] += a0[2] * b[j];  acc[3][j] += a0[3] * b[j];
        acc[4][j] += a1[0] * b[j];  acc[5][j] += a1[1] * b[j];
        acc[6][j] += a1[2] * b[j];  acc[7][j] += a1[3] * b[j];
      }
    }
  }
  fx4 bv4 = *(const fx4*)&bias[bn + tnc];
  if constexpr (OUTMODE == 0) {
    float* C = (float*)Cv;
    #pragma unroll
    for (int i = 0; i < 8; ++i) {
      const size_t row = (size_t)(bm + tmr + i);
      fx4 v = {acc[i][0], acc[i][1], acc[i][2], acc[i][3]};
      v += bv4;
      if constexpr (RES) v += *(const fx4*)&res[row * N + bn + tnc];
      if constexpr (RELU) {
        #pragma unroll
        for (int c = 0; c < 4; ++c) v[c] = fmaxf(v[c], 0.f);
      }
      *(fx4*)&C[row * N + bn + tnc] = v;
    }
  } else {
    ushort_t* C = (ushort_t*)Cv;
    #pragma unroll
    for (int j = 0; j < 4; ++j) {
      s16x8 w;
      #pragma unroll
      for (int i = 0; i < 8; ++i) w[i] = f2bf(acc[i][j] + bv4[j]);
      *(s16x8*)&C[(size_t)(bn + tnc + j) * M + bm + tmr] = w;
    }
  }
}

// ---------------------------------------------------------------------------
// adj @ x with bf16 MFMA. A = adj fp32 [8192][8192] (converted on the fly),
// B = xT bf16 [256][8192] (x transposed; frag = 8 contiguous k).
// BM=64, BN=256 (full N -> adj fetched once), BK=64, K split 4 ways.
// grid (4 ksplit, 128 mblocks), 256 thr (4 waves; wave w owns cols w*64..+63).
// Writes fp32 partials; relu_reduce4 sums + relu.
// ---------------------------------------------------------------------------
__global__ __launch_bounds__(256) void adjmm_kernel(
    const float* __restrict__ adj, const ushort_t* __restrict__ xT,
    float* __restrict__ part) {
  __shared__ __align__(16) ushort_t Asm[64 * 72];    // stride 72 el = 36 words
  __shared__ __align__(16) ushort_t Bsm[256 * 72];
  const int t = threadIdx.x;
  const int lane = t & 63, wave = t >> 6;
  const int bm = blockIdx.y * 64;
  const int kh = blockIdx.x;                 // K chunk: kh*2048 .. +2047
  const int wn = wave * 64;
  const int fr = lane & 15, fq = lane >> 4;
  fx4 acc[4][4] = {};
  const int ar = t >> 2, aq = (t & 3) * 16;
  const float*    Ag = adj + (size_t)(bm + ar) * 8192 + kh * 2048 + aq;
  const ushort_t* Bg = xT  + (size_t)t * 8192 + kh * 2048;
  for (int kt = 0; kt < 32; ++kt) {
    const int k0 = kt * 64;
    fx4 a0 = *(const fx4*)(Ag + k0);
    fx4 a1 = *(const fx4*)(Ag + k0 + 4);
    fx4 a2 = *(const fx4*)(Ag + k0 + 8);
    fx4 a3 = *(const fx4*)(Ag + k0 + 12);
    s16x8 bvec[8];
    #pragma unroll
    for (int c = 0; c < 8; ++c) bvec[c] = *(const s16x8*)(Bg + k0 + c * 8);
    __syncthreads();
    s16x8 w0, w1;
    w0[0]=f2bf(a0[0]); w0[1]=f2bf(a0[1]); w0[2]=f2bf(a0[2]); w0[3]=f2bf(a0[3]);
    w0[4]=f2bf(a1[0]); w0[5]=f2bf(a1[1]); w0[6]=f2bf(a1[2]); w0[7]=f2bf(a1[3]);
    w1[0]=f2bf(a2[0]); w1[1]=f2bf(a2[1]); w1[2]=f2bf(a2[2]); w1[3]=f2bf(a2[3]);
    w1[4]=f2bf(a3[0]); w1[5]=f2bf(a3[1]); w1[6]=f2bf(a3[2]); w1[7]=f2bf(a3[3]);
    *(s16x8*)&Asm[ar * 72 + aq]     = w0;
    *(s16x8*)&Asm[ar * 72 + aq + 8] = w1;
    #pragma unroll
    for (int c = 0; c < 8; ++c) *(s16x8*)&Bsm[t * 72 + c * 8] = bvec[c];
    __syncthreads();
    #pragma unroll
    for (int kk = 0; kk < 2; ++kk) {
      s16x8 af[4], bf[4];
      #pragma unroll
      for (int mf = 0; mf < 4; ++mf)
        af[mf] = *(const s16x8*)&Asm[(mf * 16 + fr) * 72 + kk * 32 + fq * 8];
      #pragma unroll
      for (int nf = 0; nf < 4; ++nf)
        bf[nf] = *(const s16x8*)&Bsm[(wn + nf * 16 + fr) * 72 + kk * 32 + fq * 8];
      #pragma unroll
      for (int mf = 0; mf < 4; ++mf) {
        #pragma unroll
        for (int nf = 0; nf < 4; ++nf)
          acc[mf][nf] = __builtin_amdgcn_mfma_f32_16x16x32_bf16(
              af[mf], bf[nf], acc[mf][nf], 0, 0, 0);
      }
    }
  }
  float* po = part + (size_t)kh * (8192ull * 256ull);
  #pragma unroll
  for (int mf = 0; mf < 4; ++mf) {
    #pragma unroll
    for (int nf = 0; nf < 4; ++nf) {
      #pragma unroll
      for (int r = 0; r < 4; ++r)
        po[(size_t)(bm + mf * 16 + fq * 4 + r) * 256 + wn + nf * 16 + fr] =
            acc[mf][nf][r];
    }
  }
}

__global__ __launch_bounds__(256) void relu_reduce4(
    const float* __restrict__ part, float* __restrict__ p) {
  const size_t i = ((size_t)blockIdx.x * 256 + threadIdx.x) * 4;
  const size_t S = 8192ull * 256ull;
  fx4 v = *(const fx4*)(part + i);
  v += *(const fx4*)(part + S + i);
  v += *(const fx4*)(part + 2 * S + i);
  v += *(const fx4*)(part + 3 * S + i);
  #pragma unroll
  for (int c = 0; c < 4; ++c) v[c] = fmaxf(v[c], 0.f);
  *(fx4*)(p + i) = v;
}

// ---------------------------------------------------------------------------
// Attention. One block per (graph b, head h). 128 q-rows, 128 k-rows, d=64.
// attA: scores + softmax -> S holds exp(s-m), rowsum holds denominators.
// attB: (S @ V) / rowsum -> attout [8192][256] head-interleaved.
// ---------------------------------------------------------------------------
__global__ __launch_bounds__(128) void attA_kernel(
    const float* __restrict__ qkv, float* __restrict__ S,
    float* __restrict__ rowsum) {
  __shared__ float k_s[128][68];
  __shared__ float s_s[128][133];   // stride 133 (odd*?): banks spread
  const int bh = blockIdx.x, b = bh >> 2, h = bh & 3;
  const int t = threadIdx.x;
  const float* base = qkv + (size_t)b * 128 * 768 + h * 64;
  for (int e = t; e < 128 * 64; e += 128) {
    int n = e >> 6, d = e & 63;
    k_s[n][d] = base[(size_t)n * 768 + 256 + d];
  }
  fx4 qr[16];
  const fx4* qrow = (const fx4*)(base + (size_t)t * 768);
  #pragma unroll
  for (int c = 0; c < 16; ++c) qr[c] = qrow[c];
  __syncthreads();
  float m = -1e30f;
  for (int j = 0; j < 128; ++j) {
    const fx4* kr = (const fx4*)&k_s[j][0];
    float s0 = 0.f, s1 = 0.f, s2 = 0.f, s3 = 0.f;
    #pragma unroll
    for (int c = 0; c < 16; c += 4) {
      fx4 k0 = kr[c], k1 = kr[c + 1], k2 = kr[c + 2], k3 = kr[c + 3];
      s0 += qr[c][0]*k0[0] + qr[c][1]*k0[1] + qr[c][2]*k0[2] + qr[c][3]*k0[3];
      s1 += qr[c+1][0]*k1[0] + qr[c+1][1]*k1[1] + qr[c+1][2]*k1[2] + qr[c+1][3]*k1[3];
      s2 += qr[c+2][0]*k2[0] + qr[c+2][1]*k2[1] + qr[c+2][2]*k2[2] + qr[c+2][3]*k2[3];
      s3 += qr[c+3][0]*k3[0] + qr[c+3][1]*k3[1] + qr[c+3][2]*k3[2] + qr[c+3][3]*k3[3];
    }
    float s = (s0 + s1 + s2 + s3) * 0.125f;
    s_s[t][j] = s;
    m = fmaxf(m, s);
  }
  float sum = 0.f;
  float* Srow = S + (size_t)(bh * 128 + t) * 128;
  for (int j = 0; j < 128; ++j) {
    float e = __expf(s_s[t][j] - m);
    sum += e;
    Srow[j] = e;
  }
  rowsum[bh * 128 + t] = sum;
}

__global__ __launch_bounds__(256) void attB_kernel(
    const float* __restrict__ qkv, const float* __restrict__ S,
    const float* __restrict__ rowsum, float* __restrict__ attout) {
  __shared__ float v_s[128][68];
  const int bh = blockIdx.x, b = bh >> 2, h = bh & 3;
  const int t = threadIdx.x;
  const float* base = qkv + (size_t)b * 128 * 768 + h * 64;
  for (int e = t; e < 128 * 64; e += 256) {
    int n = e >> 6, d = e & 63;
    v_s[n][d] = base[(size_t)n * 768 + 512 + d];
  }
  __syncthreads();
  const int row = t >> 1, dh = (t & 1) * 32;
  const fx4* Srow4 = (const fx4*)(S + (size_t)(bh * 128 + row) * 128);
  fx4 acc4[8] = {};
  for (int k4 = 0; k4 < 32; ++k4) {
    fx4 e4 = Srow4[k4];
    const int k = k4 * 4;
    #pragma unroll
    for (int kk = 0; kk < 4; ++kk) {
      const float ev = e4[kk];
      const fx4* vr = (const fx4*)&v_s[k + kk][dh];
      #pragma unroll
      for (int c = 0; c < 8; ++c) acc4[c] += ev * vr[c];
    }
  }
  const float inv = 1.f / rowsum[bh * 128 + row];
  float* orow = attout + (size_t)(b * 128 + row) * 256 + h * 64 + dh;
  #pragma unroll
  for (int c = 0; c < 8; ++c) *(fx4*)(orow + c * 4) = acc4[c] * inv;
}

// ---------------------------------------------------------------------------
// LayerNorm over H=256. One wave per row, 4 rows per block.
// ---------------------------------------------------------------------------
__global__ __launch_bounds__(256) void ln_kernel(
    const float* __restrict__ z, const float* __restrict__ gs,
    const float* __restrict__ gb, float* __restrict__ o) {
  const int t = threadIdx.x, lane = t & 63, w = t >> 6;
  const int row = blockIdx.x * 4 + w;
  const fx4* zr = (const fx4*)(z + (size_t)row * 256);
  fx4 v = zr[lane];
  float s = v[0] + v[1] + v[2] + v[3];
  #pragma unroll
  for (int off = 1; off < 64; off <<= 1) s += __shfl_xor(s, off, 64);
  const float mu = s * (1.f / 256.f);
  fx4 xc = v - mu;
  float q = xc[0]*xc[0] + xc[1]*xc[1] + xc[2]*xc[2] + xc[3]*xc[3];
  #pragma unroll
  for (int off = 1; off < 64; off <<= 1) q += __shfl_xor(q, off, 64);
  const float r = rsqrtf(q * (1.f / 256.f) + 1e-5f);
  fx4 sv = ((const fx4*)gs)[lane], bv = ((const fx4*)gb)[lane];
  fx4 ov = xc * r * sv + bv;
  ((fx4*)(o + (size_t)row * 256))[lane] = ov;
}

// ---------------------------------------------------------------------------
// Pool: sum 128 rows per graph. grid 64, thread h sums column h.
// ---------------------------------------------------------------------------
__global__ __launch_bounds__(256) void pool_kernel(
    const float* __restrict__ y2, float* __restrict__ pooled) {
  const int b = blockIdx.x, h = threadIdx.x;
  const float* pb = y2 + (size_t)b * 128 * 256 + h;
  float s = 0.f;
  for (int n = 0; n < 128; ++n) s += pb[(size_t)n * 256];
  pooled[b * 256 + h] = s;
}

// ---------------------------------------------------------------------------
// Head: relu(pooled@W3+b3)@W4+b4 -> log_softmax. grid 64 (one block/graph).
// ---------------------------------------------------------------------------
__global__ __launch_bounds__(256) void head_kernel(
    const float* __restrict__ pooled, const float* __restrict__ W3,
    const float* __restrict__ b3, const float* __restrict__ W4,
    const float* __restrict__ b4, float* __restrict__ out) {
  __shared__ float t1[256];
  __shared__ float logits[16];
  const int b = blockIdx.x, h = threadIdx.x;
  float a = b3[h];
  const float* pb = pooled + b * 256;
  for (int k = 0; k < 256; ++k) a += pb[k] * W3[k * 256 + h];
  t1[h] = fmaxf(a, 0.f);
  __syncthreads();
  if (h < 16) {
    float o = b4[h];
    for (int j = 0; j < 256; ++j) o += t1[j] * W4[j * 16 + h];
    logits[h] = o;
  }
  __syncthreads();
  if (h < 16) {
    float m = -1e30f;
    #pragma unroll
    for (int c = 0; c < 16; ++c) m = fmaxf(m, logits[c]);
    float se = 0.f;
    #pragma unroll
    for (int c = 0; c < 16; ++c) se += __expf(logits[c] - m);
    out[b * 16 + h] = logits[h] - m - logf(se);
  }
}

// ---------------------------------------------------------------------------
extern "C" void kernel_launch(void* const* d_in, const int* in_sizes, int n_in,
                              void* d_out, int out_size, void* d_ws, size_t ws_size,
                              hipStream_t stream) {
  const float* x_in  = (const float*)d_in[0];
  const float* adj   = (const float*)d_in[1];
  const float* W1    = (const float*)d_in[4];
  const float* b1    = (const float*)d_in[5];
  const float* in_w  = (const float*)d_in[6];
  const float* in_b  = (const float*)d_in[7];
  const float* out_w = (const float*)d_in[8];
  const float* out_b = (const float*)d_in[9];
  const float* ln1_s = (const float*)d_in[10];
  const float* ln1_b = (const float*)d_in[11];
  const float* ff1_w = (const float*)d_in[12];
  const float* ff1_b = (const float*)d_in[13];
  const float* ff2_w = (const float*)d_in[14];
  const float* ff2_b = (const float*)d_in[15];
  const float* ln2_s = (const float*)d_in[16];
  const float* ln2_b = (const float*)d_in[17];
  const float* W3    = (const float*)d_in[18];
  const float* b3    = (const float*)d_in[19];
  const float* W4    = (const float*)d_in[20];
  const float* b4    = (const float*)d_in[21];
  char* ws = (char*)d_ws;
  ushort_t* xT   = (ushort_t*)(ws);                       // 4 MB  bf16 x^T
  float* p       = (float*)(ws + (4ull  << 20));          // 8 MB
  float* qkvb    = (float*)(ws + (12ull << 20));          // 24 MB
  float* S       = (float*)(ws + (36ull << 20));          // 16 MB
  float* rowsum  = (float*)(ws + (52ull << 20));          // 128 KB
  float* pooled  = (float*)(ws + (52ull << 20) + (512ull << 10)); // 64 KB
  float* attout  = (float*)(ws + (53ull << 20));          // 8 MB
  float* z1      = (float*)(ws + (61ull << 20));          // 8 MB
  float* y       = (float*)(ws + (69ull << 20));          // 8 MB
  float* part    = (float*)(ws + (77ull << 20));          // 32 MB (adj partials)
  float* f1      = (float*)(ws + (12ull << 20));          // reuse qkv
  float* z2      = (float*)(ws + (36ull << 20));          // reuse S
  float* y2      = (float*)(ws + (44ull << 20));          // reuse S
  float* outp    = (float*)d_out;
  (void)in_sizes; (void)n_in; (void)out_size; (void)ws_size;

  // fc1: x = x_in@W1 + b1, stored transposed bf16 (B operand of adjmm)
  gemm128<1, false, false><<<dim3(4, 64), 256, 0, stream>>>(
      x_in, W1, b1, nullptr, xT, 8192, 256, 256);
  // p = relu(adj @ x)
  adjmm_kernel<<<dim3(4, 128), 256, 0, stream>>>(adj, xT, part);
  relu_reduce4<<<2048, 256, 0, stream>>>(part, p);
  // qkv
  gemm128<0, false, false><<<dim3(12, 64), 256, 0, stream>>>(
      p, in_w, in_b, nullptr, qkvb, 8192, 768, 256);
  // attention
  attA_kernel<<<256, 128, 0, stream>>>(qkvb, S, rowsum);
  attB_kernel<<<256, 256, 0, stream>>>(qkvb, S, rowsum, attout);
  // out projection + residual(p)
  gemm128<0, false, true><<<dim3(4, 64), 256, 0, stream>>>(
      attout, out_w, out_b, p, z1, 8192, 256, 256);
  ln_kernel<<<2048, 256, 0, stream>>>(z1, ln1_s, ln1_b, y);
  // FFN
  gemm128<0, true, false><<<dim3(8, 64), 256, 0, stream>>>(
      y, ff1_w, ff1_b, nullptr, f1, 8192, 512, 256);
  gemm128<0, false, true><<<dim3(4, 64), 256, 0, stream>>>(
      f1, ff2_w, ff2_b, y, z2, 8192, 256, 512);
  ln_kernel<<<2048, 256, 0, stream>>>(z2, ln2_s, ln2_b, y2);
  // pooling + classifier head
  pool_kernel<<<64, 256, 0, stream>>>(y2, pooled);
  head_kernel<<<64, 256, 0, stream>>>(pooled, W3, b3, W4, b4, outp);
}

// Round 2
// 319.487 us; speedup vs baseline: 1.2748x; 1.2748x over previous
//
#include <hip/hip_runtime.h>

typedef float fx4 __attribute__((ext_vector_type(4)));
typedef short s16x8 __attribute__((ext_vector_type(8)));
typedef short s16x4 __attribute__((ext_vector_type(4)));
typedef unsigned short ushort_t;

__device__ __forceinline__ short f2bf(float f) {
  union { float f; unsigned u; } v; v.f = f;
  unsigned r = v.u + 0x7FFFu + ((v.u >> 16) & 1u);   // RNE to bf16
  return (short)(r >> 16);
}

// ---------------------------------------------------------------------------
// cvt fp32 -> bf16 (vectorized x4)
// ---------------------------------------------------------------------------
__global__ __launch_bounds__(256) void cvt_bf16x4(
    const float* __restrict__ X, ushort_t* __restrict__ Y, int n4) {
  int i = blockIdx.x * 256 + threadIdx.x;
  if (i < n4) {
    fx4 v = ((const fx4*)X)[i];
    s16x4 w;
    #pragma unroll
    for (int c = 0; c < 4; ++c) w[c] = f2bf(v[c]);
    ((s16x4*)Y)[i] = w;
  }
}

// W[K][N] fp32 -> Wt[N][K] bf16 (weights are tiny; strided writes are fine)
__global__ __launch_bounds__(256) void wtrans_kernel(
    const float* __restrict__ W, ushort_t* __restrict__ Wt, int K, int N) {
  int idx = blockIdx.x * 256 + threadIdx.x;
  if (idx < K * N) {
    int k = idx / N, n = idx - k * N;
    Wt[(size_t)n * K + k] = (ushort_t)f2bf(W[idx]);
  }
}

// ---------------------------------------------------------------------------
// MFMA GEMM: C[M,N] = A@B + bias (+res)(+relu).  A bf16 [M,K], Bt bf16 [N,K].
// BM=64, BN=256, 256 thr (4 waves; wave w owns cols w*64..+63), BK=64.
// TRANSOUT: write only bf16 C^T [N][M] (4-contig rows per 8B store).
// ---------------------------------------------------------------------------
template<bool RELU, bool RES, bool F32OUT, bool BF16OUT, bool TRANSOUT>
__global__ __launch_bounds__(256) void mgemm(
    const ushort_t* __restrict__ A, const ushort_t* __restrict__ Bt,
    const float* __restrict__ bias, const float* __restrict__ res,
    float* __restrict__ Cf, ushort_t* __restrict__ Cb, int M, int N, int K) {
  __shared__ __align__(16) ushort_t Asm[64 * 72];
  __shared__ __align__(16) ushort_t Bsm[256 * 72];
  const int t = threadIdx.x, lane = t & 63, wave = t >> 6;
  const int bm = blockIdx.y * 64, bn = blockIdx.x * 256;
  const int wn = wave * 64, fr = lane & 15, fq = lane >> 4;
  fx4 acc[4][4] = {};
  const int ar = t >> 2, aq = (t & 3) * 16;
  const ushort_t* Ag = A + (size_t)(bm + ar) * K + aq;
  const ushort_t* Bg = Bt + (size_t)(bn + t) * K;
  for (int k0 = 0; k0 < K; k0 += 64) {
    s16x8 a0 = *(const s16x8*)(Ag + k0);
    s16x8 a1 = *(const s16x8*)(Ag + k0 + 8);
    s16x8 bvec[8];
    #pragma unroll
    for (int c = 0; c < 8; ++c) bvec[c] = *(const s16x8*)(Bg + k0 + c * 8);
    __syncthreads();
    *(s16x8*)&Asm[ar * 72 + aq] = a0;
    *(s16x8*)&Asm[ar * 72 + aq + 8] = a1;
    #pragma unroll
    for (int c = 0; c < 8; ++c) *(s16x8*)&Bsm[t * 72 + c * 8] = bvec[c];
    __syncthreads();
    #pragma unroll
    for (int kk = 0; kk < 2; ++kk) {
      s16x8 af[4], bf[4];
      #pragma unroll
      for (int mf = 0; mf < 4; ++mf)
        af[mf] = *(const s16x8*)&Asm[(mf * 16 + fr) * 72 + kk * 32 + fq * 8];
      #pragma unroll
      for (int nf = 0; nf < 4; ++nf)
        bf[nf] = *(const s16x8*)&Bsm[(wn + nf * 16 + fr) * 72 + kk * 32 + fq * 8];
      #pragma unroll
      for (int mf = 0; mf < 4; ++mf)
        #pragma unroll
        for (int nf = 0; nf < 4; ++nf)
          acc[mf][nf] = __builtin_amdgcn_mfma_f32_16x16x32_bf16(
              af[mf], bf[nf], acc[mf][nf], 0, 0, 0);
    }
  }
  if constexpr (TRANSOUT) {
    #pragma unroll
    for (int mf = 0; mf < 4; ++mf)
      #pragma unroll
      for (int nf = 0; nf < 4; ++nf) {
        const int col = bn + wn + nf * 16 + fr;
        const float bb = bias[col];
        s16x4 w;
        #pragma unroll
        for (int r = 0; r < 4; ++r) w[r] = f2bf(acc[mf][nf][r] + bb);
        *(s16x4*)&Cb[(size_t)col * M + bm + mf * 16 + fq * 4] = w;
      }
  } else {
    #pragma unroll
    for (int mf = 0; mf < 4; ++mf)
      #pragma unroll
      for (int nf = 0; nf < 4; ++nf) {
        const int col = bn + wn + nf * 16 + fr;
        const float bb = bias[col];
        #pragma unroll
        for (int r = 0; r < 4; ++r) {
          const int row = bm + mf * 16 + fq * 4 + r;
          float v = acc[mf][nf][r] + bb;
          if constexpr (RES) v += res[(size_t)row * N + col];
          if constexpr (RELU) v = fmaxf(v, 0.f);
          if constexpr (F32OUT) Cf[(size_t)row * N + col] = v;
          if constexpr (BF16OUT) Cb[(size_t)row * N + col] = (ushort_t)f2bf(v);
        }
      }
  }
}

// ---------------------------------------------------------------------------
// adj @ x with bf16 MFMA (unchanged from round 1; ref-checked).
// ---------------------------------------------------------------------------
__global__ __launch_bounds__(256) void adjmm_kernel(
    const float* __restrict__ adj, const ushort_t* __restrict__ xT,
    float* __restrict__ part) {
  __shared__ __align__(16) ushort_t Asm[64 * 72];
  __shared__ __align__(16) ushort_t Bsm[256 * 72];
  const int t = threadIdx.x;
  const int lane = t & 63, wave = t >> 6;
  const int bm = blockIdx.y * 64;
  const int kh = blockIdx.x;
  const int wn = wave * 64;
  const int fr = lane & 15, fq = lane >> 4;
  fx4 acc[4][4] = {};
  const int ar = t >> 2, aq = (t & 3) * 16;
  const float*    Ag = adj + (size_t)(bm + ar) * 8192 + kh * 2048 + aq;
  const ushort_t* Bg = xT  + (size_t)t * 8192 + kh * 2048;
  for (int kt = 0; kt < 32; ++kt) {
    const int k0 = kt * 64;
    fx4 a0 = *(const fx4*)(Ag + k0);
    fx4 a1 = *(const fx4*)(Ag + k0 + 4);
    fx4 a2 = *(const fx4*)(Ag + k0 + 8);
    fx4 a3 = *(const fx4*)(Ag + k0 + 12);
    s16x8 bvec[8];
    #pragma unroll
    for (int c = 0; c < 8; ++c) bvec[c] = *(const s16x8*)(Bg + k0 + c * 8);
    __syncthreads();
    s16x8 w0, w1;
    w0[0]=f2bf(a0[0]); w0[1]=f2bf(a0[1]); w0[2]=f2bf(a0[2]); w0[3]=f2bf(a0[3]);
    w0[4]=f2bf(a1[0]); w0[5]=f2bf(a1[1]); w0[6]=f2bf(a1[2]); w0[7]=f2bf(a1[3]);
    w1[0]=f2bf(a2[0]); w1[1]=f2bf(a2[1]); w1[2]=f2bf(a2[2]); w1[3]=f2bf(a2[3]);
    w1[4]=f2bf(a3[0]); w1[5]=f2bf(a3[1]); w1[6]=f2bf(a3[2]); w1[7]=f2bf(a3[3]);
    *(s16x8*)&Asm[ar * 72 + aq]     = w0;
    *(s16x8*)&Asm[ar * 72 + aq + 8] = w1;
    #pragma unroll
    for (int c = 0; c < 8; ++c) *(s16x8*)&Bsm[t * 72 + c * 8] = bvec[c];
    __syncthreads();
    #pragma unroll
    for (int kk = 0; kk < 2; ++kk) {
      s16x8 af[4], bf[4];
      #pragma unroll
      for (int mf = 0; mf < 4; ++mf)
        af[mf] = *(const s16x8*)&Asm[(mf * 16 + fr) * 72 + kk * 32 + fq * 8];
      #pragma unroll
      for (int nf = 0; nf < 4; ++nf)
        bf[nf] = *(const s16x8*)&Bsm[(wn + nf * 16 + fr) * 72 + kk * 32 + fq * 8];
      #pragma unroll
      for (int mf = 0; mf < 4; ++mf)
        #pragma unroll
        for (int nf = 0; nf < 4; ++nf)
          acc[mf][nf] = __builtin_amdgcn_mfma_f32_16x16x32_bf16(
              af[mf], bf[nf], acc[mf][nf], 0, 0, 0);
    }
  }
  float* po = part + (size_t)kh * (8192ull * 256ull);
  #pragma unroll
  for (int mf = 0; mf < 4; ++mf)
    #pragma unroll
    for (int nf = 0; nf < 4; ++nf)
      #pragma unroll
      for (int r = 0; r < 4; ++r)
        po[(size_t)(bm + mf * 16 + fq * 4 + r) * 256 + wn + nf * 16 + fr] =
            acc[mf][nf][r];
}

__global__ __launch_bounds__(256) void relu_reduce4(
    const float* __restrict__ part, float* __restrict__ p,
    ushort_t* __restrict__ pb) {
  const size_t i = ((size_t)blockIdx.x * 256 + threadIdx.x) * 4;
  const size_t S = 8192ull * 256ull;
  fx4 v = *(const fx4*)(part + i);
  v += *(const fx4*)(part + S + i);
  v += *(const fx4*)(part + 2 * S + i);
  v += *(const fx4*)(part + 3 * S + i);
  #pragma unroll
  for (int c = 0; c < 4; ++c) v[c] = fmaxf(v[c], 0.f);
  *(fx4*)(p + i) = v;
  s16x4 w;
  #pragma unroll
  for (int c = 0; c < 4; ++c) w[c] = f2bf(v[c]);
  *(s16x4*)(pb + i) = w;
}

// ---------------------------------------------------------------------------
// Attention (fp32, unchanged structure). attB now emits bf16 attout.
// ---------------------------------------------------------------------------
__global__ __launch_bounds__(128) void attA_kernel(
    const float* __restrict__ qkv, float* __restrict__ S,
    float* __restrict__ rowsum) {
  __shared__ float k_s[128][68];
  __shared__ float s_s[128][133];
  const int bh = blockIdx.x, b = bh >> 2, h = bh & 3;
  const int t = threadIdx.x;
  const float* base = qkv + (size_t)b * 128 * 768 + h * 64;
  for (int e = t; e < 128 * 64; e += 128) {
    int n = e >> 6, d = e & 63;
    k_s[n][d] = base[(size_t)n * 768 + 256 + d];
  }
  fx4 qr[16];
  const fx4* qrow = (const fx4*)(base + (size_t)t * 768);
  #pragma unroll
  for (int c = 0; c < 16; ++c) qr[c] = qrow[c];
  __syncthreads();
  float m = -1e30f;
  for (int j = 0; j < 128; ++j) {
    const fx4* kr = (const fx4*)&k_s[j][0];
    float s0 = 0.f, s1 = 0.f, s2 = 0.f, s3 = 0.f;
    #pragma unroll
    for (int c = 0; c < 16; c += 4) {
      fx4 k0 = kr[c], k1 = kr[c + 1], k2 = kr[c + 2], k3 = kr[c + 3];
      s0 += qr[c][0]*k0[0] + qr[c][1]*k0[1] + qr[c][2]*k0[2] + qr[c][3]*k0[3];
      s1 += qr[c+1][0]*k1[0] + qr[c+1][1]*k1[1] + qr[c+1][2]*k1[2] + qr[c+1][3]*k1[3];
      s2 += qr[c+2][0]*k2[0] + qr[c+2][1]*k2[1] + qr[c+2][2]*k2[2] + qr[c+2][3]*k2[3];
      s3 += qr[c+3][0]*k3[0] + qr[c+3][1]*k3[1] + qr[c+3][2]*k3[2] + qr[c+3][3]*k3[3];
    }
    float s = (s0 + s1 + s2 + s3) * 0.125f;
    s_s[t][j] = s;
    m = fmaxf(m, s);
  }
  float sum = 0.f;
  float* Srow = S + (size_t)(bh * 128 + t) * 128;
  for (int j = 0; j < 128; ++j) {
    float e = __expf(s_s[t][j] - m);
    sum += e;
    Srow[j] = e;
  }
  rowsum[bh * 128 + t] = sum;
}

__global__ __launch_bounds__(256) void attB_kernel(
    const float* __restrict__ qkv, const float* __restrict__ S,
    const float* __restrict__ rowsum, ushort_t* __restrict__ attout) {
  __shared__ float v_s[128][68];
  const int bh = blockIdx.x, b = bh >> 2, h = bh & 3;
  const int t = threadIdx.x;
  const float* base = qkv + (size_t)b * 128 * 768 + h * 64;
  for (int e = t; e < 128 * 64; e += 256) {
    int n = e >> 6, d = e & 63;
    v_s[n][d] = base[(size_t)n * 768 + 512 + d];
  }
  __syncthreads();
  const int row = t >> 1, dh = (t & 1) * 32;
  const fx4* Srow4 = (const fx4*)(S + (size_t)(bh * 128 + row) * 128);
  fx4 acc4[8] = {};
  for (int k4 = 0; k4 < 32; ++k4) {
    fx4 e4 = Srow4[k4];
    const int k = k4 * 4;
    #pragma unroll
    for (int kk = 0; kk < 4; ++kk) {
      const float ev = e4[kk];
      const fx4* vr = (const fx4*)&v_s[k + kk][dh];
      #pragma unroll
      for (int c = 0; c < 8; ++c) acc4[c] += ev * vr[c];
    }
  }
  const float inv = 1.f / rowsum[bh * 128 + row];
  ushort_t* orow = attout + (size_t)(b * 128 + row) * 256 + h * 64 + dh;
  #pragma unroll
  for (int c = 0; c < 8; ++c) {
    fx4 v = acc4[c] * inv;
    s16x4 w;
    #pragma unroll
    for (int j = 0; j < 4; ++j) w[j] = f2bf(v[j]);
    *(s16x4*)(orow + c * 4) = w;
  }
}

// ---------------------------------------------------------------------------
// LayerNorm over H=256; optional bf16 copy.
// ---------------------------------------------------------------------------
__global__ __launch_bounds__(256) void ln_kernel(
    const float* __restrict__ z, const float* __restrict__ gs,
    const float* __restrict__ gb, float* __restrict__ o,
    ushort_t* __restrict__ ob) {
  const int t = threadIdx.x, lane = t & 63, w = t >> 6;
  const int row = blockIdx.x * 4 + w;
  const fx4* zr = (const fx4*)(z + (size_t)row * 256);
  fx4 v = zr[lane];
  float s = v[0] + v[1] + v[2] + v[3];
  #pragma unroll
  for (int off = 1; off < 64; off <<= 1) s += __shfl_xor(s, off, 64);
  const float mu = s * (1.f / 256.f);
  fx4 xc = v - mu;
  float q = xc[0]*xc[0] + xc[1]*xc[1] + xc[2]*xc[2] + xc[3]*xc[3];
  #pragma unroll
  for (int off = 1; off < 64; off <<= 1) q += __shfl_xor(q, off, 64);
  const float r = rsqrtf(q * (1.f / 256.f) + 1e-5f);
  fx4 sv = ((const fx4*)gs)[lane], bv = ((const fx4*)gb)[lane];
  fx4 ov = xc * r * sv + bv;
  ((fx4*)(o + (size_t)row * 256))[lane] = ov;
  if (ob) {
    s16x4 wv;
    #pragma unroll
    for (int c = 0; c < 4; ++c) wv[c] = f2bf(ov[c]);
    ((s16x4*)(ob + (size_t)row * 256))[lane] = wv;
  }
}

// Pool: 4 blocks per graph, each sums 32 rows.
__global__ __launch_bounds__(256) void pool_kernel(
    const float* __restrict__ y2, float* __restrict__ pooled4) {
  const int bq = blockIdx.x;
  const int b = bq >> 2, q = bq & 3, h = threadIdx.x;
  const float* pb = y2 + ((size_t)b * 128 + q * 32) * 256 + h;
  float s = 0.f;
  for (int n = 0; n < 32; ++n) s += pb[(size_t)n * 256];
  pooled4[(size_t)bq * 256 + h] = s;
}

__global__ __launch_bounds__(256) void head_kernel(
    const float* __restrict__ pooled4, const float* __restrict__ W3,
    const float* __restrict__ b3, const float* __restrict__ W4,
    const float* __restrict__ b4, float* __restrict__ out) {
  __shared__ float sp[256];
  __shared__ float t1[256];
  __shared__ float logits[16];
  const int b = blockIdx.x, h = threadIdx.x;
  sp[h] = pooled4[(size_t)(b * 4 + 0) * 256 + h] +
          pooled4[(size_t)(b * 4 + 1) * 256 + h] +
          pooled4[(size_t)(b * 4 + 2) * 256 + h] +
          pooled4[(size_t)(b * 4 + 3) * 256 + h];
  __syncthreads();
  float a = b3[h];
  for (int k = 0; k < 256; ++k) a += sp[k] * W3[k * 256 + h];
  t1[h] = fmaxf(a, 0.f);
  __syncthreads();
  if (h < 16) {
    float o = b4[h];
    for (int j = 0; j < 256; ++j) o += t1[j] * W4[j * 16 + h];
    logits[h] = o;
  }
  __syncthreads();
  if (h < 16) {
    float m = -1e30f;
    #pragma unroll
    for (int c = 0; c < 16; ++c) m = fmaxf(m, logits[c]);
    float se = 0.f;
    #pragma unroll
    for (int c = 0; c < 16; ++c) se += __expf(logits[c] - m);
    out[b * 16 + h] = logits[h] - m - logf(se);
  }
}

// ---------------------------------------------------------------------------
extern "C" void kernel_launch(void* const* d_in, const int* in_sizes, int n_in,
                              void* d_out, int out_size, void* d_ws, size_t ws_size,
                              hipStream_t stream) {
  const float* x_in  = (const float*)d_in[0];
  const float* adj   = (const float*)d_in[1];
  const float* W1    = (const float*)d_in[4];
  const float* b1    = (const float*)d_in[5];
  const float* in_w  = (const float*)d_in[6];
  const float* in_b  = (const float*)d_in[7];
  const float* out_w = (const float*)d_in[8];
  const float* out_b = (const float*)d_in[9];
  const float* ln1_s = (const float*)d_in[10];
  const float* ln1_b = (const float*)d_in[11];
  const float* ff1_w = (const float*)d_in[12];
  const float* ff1_b = (const float*)d_in[13];
  const float* ff2_w = (const float*)d_in[14];
  const float* ff2_b = (const float*)d_in[15];
  const float* ln2_s = (const float*)d_in[16];
  const float* ln2_b = (const float*)d_in[17];
  const float* W3    = (const float*)d_in[18];
  const float* b3    = (const float*)d_in[19];
  const float* W4    = (const float*)d_in[20];
  const float* b4    = (const float*)d_in[21];
  char* ws = (char*)d_ws;
  const size_t MB = 1ull << 20;
  ushort_t* xT      = (ushort_t*)(ws);                 // 4 MB
  ushort_t* x_in_bf = (ushort_t*)(ws + 4 * MB);        // 4 MB
  ushort_t* W1t     = (ushort_t*)(ws + 8 * MB);
  ushort_t* in_wT   = (ushort_t*)(ws + 8 * MB + 131072);
  ushort_t* out_wT  = (ushort_t*)(ws + 8 * MB + 524288);
  ushort_t* ff1_wT  = (ushort_t*)(ws + 8 * MB + 655360);
  ushort_t* ff2_wT  = (ushort_t*)(ws + 8 * MB + 917504);
  float*    p       = (float*)(ws + 10 * MB);          // 8 MB
  ushort_t* p_bf    = (ushort_t*)(ws + 18 * MB);       // 4 MB
  float*    qkvb    = (float*)(ws + 22 * MB);          // 24 MB
  float*    S       = (float*)(ws + 46 * MB);          // 16 MB
  float*    rowsum  = (float*)(ws + 62 * MB);          // 128 KB
  ushort_t* attout  = (ushort_t*)(ws + 63 * MB);       // 4 MB
  float*    z1      = (float*)(ws + 67 * MB);          // 8 MB
  float*    y       = (float*)(ws + 75 * MB);          // 8 MB
  ushort_t* y_bf    = (ushort_t*)(ws + 83 * MB);       // 4 MB
  ushort_t* f1_bf   = (ushort_t*)(ws + 87 * MB);       // 8 MB
  float*    z2      = (float*)(ws + 95 * MB);          // 8 MB
  float*    y2      = (float*)(ws + 103 * MB);         // 8 MB
  float*    pooled4 = (float*)(ws + 111 * MB);         // 256 KB
  float*    part    = (float*)(ws + 112 * MB);         // 32 MB
  float*    outp    = (float*)d_out;
  (void)in_sizes; (void)n_in; (void)out_size; (void)ws_size;

  // input + weight conversions
  cvt_bf16x4<<<2048, 256, 0, stream>>>(x_in, x_in_bf, 8192 * 256 / 4);
  wtrans_kernel<<<256, 256, 0, stream>>>(W1, W1t, 256, 256);
  wtrans_kernel<<<768, 256, 0, stream>>>(in_w, in_wT, 256, 768);
  wtrans_kernel<<<256, 256, 0, stream>>>(out_w, out_wT, 256, 256);
  wtrans_kernel<<<512, 256, 0, stream>>>(ff1_w, ff1_wT, 256, 512);
  wtrans_kernel<<<512, 256, 0, stream>>>(ff2_w, ff2_wT, 512, 256);

  // fc1: xT = (x_in@W1+b1)^T in bf16 (B operand of adjmm)
  mgemm<false, false, false, true, true><<<dim3(1, 128), 256, 0, stream>>>(
      x_in_bf, W1t, b1, nullptr, nullptr, xT, 8192, 256, 256);
  // p = relu(adj @ x)
  adjmm_kernel<<<dim3(4, 128), 256, 0, stream>>>(adj, xT, part);
  relu_reduce4<<<2048, 256, 0, stream>>>(part, p, p_bf);
  // qkv (fp32 out for attention)
  mgemm<false, false, true, false, false><<<dim3(3, 128), 256, 0, stream>>>(
      p_bf, in_wT, in_b, nullptr, qkvb, nullptr, 8192, 768, 256);
  // attention
  attA_kernel<<<256, 128, 0, stream>>>(qkvb, S, rowsum);
  attB_kernel<<<256, 256, 0, stream>>>(qkvb, S, rowsum, attout);
  // out projection + residual(p)
  mgemm<false, true, true, false, false><<<dim3(1, 128), 256, 0, stream>>>(
      attout, out_wT, out_b, p, z1, nullptr, 8192, 256, 256);
  ln_kernel<<<2048, 256, 0, stream>>>(z1, ln1_s, ln1_b, y, y_bf);
  // FFN
  mgemm<true, false, false, true, false><<<dim3(2, 128), 256, 0, stream>>>(
      y_bf, ff1_wT, ff1_b, nullptr, nullptr, f1_bf, 8192, 512, 256);
  mgemm<false, true, true, false, false><<<dim3(1, 128), 256, 0, stream>>>(
      f1_bf, ff2_wT, ff2_b, y, z2, nullptr, 8192, 256, 512);
  ln_kernel<<<2048, 256, 0, stream>>>(z2, ln2_s, ln2_b, y2, nullptr);
  // pooling + classifier head
  pool_kernel<<<256, 256, 0, stream>>>(y2, pooled4);
  head_kernel<<<64, 256, 0, stream>>>(pooled4, W3, b3, W4, b4, outp);
}